// Round 11
// baseline (185.998 us; speedup 1.0000x reference)
//
#include <hip/hip_runtime.h>
#include <hip/hip_bf16.h>
#include <math.h>

// ---------------------------------------------------------------------------
// CrossAttention on MI355X (gfx950), bf16 MFMA pipeline, round 26.
//   cast_w: fp32 -> bf16 weights only (x/ctx cast fused into proj staging)
//   proj_qkv: 128x128, BK=64, reg-staged, fp32-A in-staging cast (R24)
//   attn: R25 32x32x16 structure + R26: T15 DOUBLE-PIPELINE — two live
//         S-states so QK(g+1)'s MFMA chains run under exp2/pack(g)'s VALU
//         work (m214v36: +7-11% on attn; MFMA and VALU are separate pipes,
//         our 2 waves/SIMD can't cover the serial QK->exp2->PV chain alone).
//         Static reg names sA*/sB* + fully-unrolled g-loop (rule #20).
//   gemm_out: 64x128, BK=64, 2-slab split-K combine (R19 form).
// ---------------------------------------------------------------------------

typedef __bf16 bf16x8 __attribute__((ext_vector_type(8)));
typedef __bf16 bf16x4 __attribute__((ext_vector_type(4)));
typedef float f32x4 __attribute__((ext_vector_type(4)));
typedef float f32x16 __attribute__((ext_vector_type(16)));

#define QSCALE 0.18033688011112042f  // 0.125 * log2(e)

#if __has_builtin(__builtin_amdgcn_exp2f)
#define EXP2(x) __builtin_amdgcn_exp2f(x)
#else
#define EXP2(x) exp2f(x)
#endif

__device__ __forceinline__ f32x4 mfma32(bf16x8 a, bf16x8 b, f32x4 c) {
  // 16x16x32: A[m=ln][k=qd*8+j], B[n=ln][k=qd*8+j]; D: row=qd*4+rg, col=ln.
  return __builtin_amdgcn_mfma_f32_16x16x32_bf16(a, b, c, 0, 0, 0);
}

__device__ __forceinline__ f32x16 mfma3216(bf16x8 a, bf16x8 b, f32x16 c) {
  // 32x32x16: A[m=lane&31][k=(lane>>5)*8+j], B[n=lane&31][k=(lane>>5)*8+j].
  // D: col=lane&31 (B's n), row=(reg&3)+8*(reg>>2)+4*(lane>>5) (A's m).
  return __builtin_amdgcn_mfma_f32_32x32x16_bf16(a, b, c, 0, 0, 0);
}

// Convert 16 fp32 (4x float4) -> 16 bf16, store as 2x uint4 at dst.
__device__ __forceinline__ void st_cast16(__bf16* dst, float4 f0, float4 f1,
                                          float4 f2, float4 f3) {
  union { __bf16 b[16]; uint4 u[2]; } cv;
  cv.b[0] = (__bf16)f0.x;  cv.b[1] = (__bf16)f0.y;
  cv.b[2] = (__bf16)f0.z;  cv.b[3] = (__bf16)f0.w;
  cv.b[4] = (__bf16)f1.x;  cv.b[5] = (__bf16)f1.y;
  cv.b[6] = (__bf16)f1.z;  cv.b[7] = (__bf16)f1.w;
  cv.b[8] = (__bf16)f2.x;  cv.b[9] = (__bf16)f2.y;
  cv.b[10] = (__bf16)f2.z; cv.b[11] = (__bf16)f2.w;
  cv.b[12] = (__bf16)f3.x; cv.b[13] = (__bf16)f3.y;
  cv.b[14] = (__bf16)f3.z; cv.b[15] = (__bf16)f3.w;
  ((uint4*)dst)[0] = cv.u[0];
  ((uint4*)dst)[1] = cv.u[1];
}

// ---------------------------------------------------------------------------
// fp32 -> bf16 cast of the four weight matrices only (~1.3M floats).
// ---------------------------------------------------------------------------
__global__ __launch_bounds__(256) void cast_w(
    const float* __restrict__ wq, const float* __restrict__ wk,
    const float* __restrict__ wv, const float* __restrict__ wo,
    __bf16* __restrict__ wqb, __bf16* __restrict__ wkb,
    __bf16* __restrict__ wvb, __bf16* __restrict__ wob) {
  const int B0 = 65536;    // wq: 512*512/4
  const int B1 = 163840;   // +wk: 512*768/4
  const int B2 = 262144;   // +wv
  const int B3 = 327680;   // +wo
  for (int i = blockIdx.x * blockDim.x + threadIdx.x; i < B3;
       i += gridDim.x * blockDim.x) {
    const float* s;
    __bf16* d;
    int off;
    if (i < B0)      { s = wq; d = wqb; off = i; }
    else if (i < B1) { s = wk; d = wkb; off = i - B0; }
    else if (i < B2) { s = wv; d = wvb; off = i - B1; }
    else             { s = wo; d = wob; off = i - B2; }
    float4 f = ((const float4*)s)[off];
    union { __bf16 b[4]; ushort4 u; } cv;
    cv.b[0] = (__bf16)f.x; cv.b[1] = (__bf16)f.y;
    cv.b[2] = (__bf16)f.z; cv.b[3] = (__bf16)f.w;
    ((ushort4*)d)[off] = cv.u;
  }
}

// ---------------------------------------------------------------------------
// 128x128 GEMM body, BK=64, register-prefetch pipeline. A is FP32 (x/ctx),
// cast to bf16 in registers during staging; W is bf16.
// MODE 0 (roles swapped): bf16 out [b,h,tok,d], 8B stores over d
// MODE 1 (natural roles): bf16 out [b,h,d,tok], 8B stores over tok
// ---------------------------------------------------------------------------
template <int MODE>
__device__ __forceinline__ void gemm_body(
    const float* __restrict__ A, const __bf16* __restrict__ W,
    __bf16* __restrict__ Cout, int Kd, float scale, int m0, int n0,
    __bf16 (*As)[72], __bf16 (*Bs)[72]) {
  const int t = threadIdx.x;
  const int w = t >> 6;
  const int lane = t & 63;
  const int ln = lane & 15;
  const int qd = lane >> 4;
  const int wm = (w >> 1) * 64;
  const int wn = (w & 1) * 64;

  f32x4 zero4 = {0.f, 0.f, 0.f, 0.f};
  f32x4 acc[4][4];
#pragma unroll
  for (int i = 0; i < 4; ++i)
#pragma unroll
    for (int j = 0; j < 4; ++j) acc[i][j] = zero4;

  const int r0 = t >> 2;          // 0..63
  const int c0 = (t & 3) * 16;    // 0/16/32/48
  const float* gA0 = A + (size_t)(m0 + r0) * Kd + c0;
  const float* gA1 = A + (size_t)(m0 + r0 + 64) * Kd + c0;
  const __bf16* gB0 = W + (size_t)(n0 + r0) * Kd + c0;
  const __bf16* gB1 = W + (size_t)(n0 + r0 + 64) * Kd + c0;

  // prologue: load tile 0 into registers (A as fp32: 4x float4 per row-half)
  float4 a0[4], a1[4];
#pragma unroll
  for (int j = 0; j < 4; ++j) {
    a0[j] = ((const float4*)gA0)[j];
    a1[j] = ((const float4*)gA1)[j];
  }
  uint4 b00 = *(const uint4*)gB0, b01 = *(const uint4*)(gB0 + 8);
  uint4 b10 = *(const uint4*)gB1, b11 = *(const uint4*)(gB1 + 8);

  for (int kc = 0; kc < Kd; kc += 64) {
    __syncthreads();  // previous iteration's frag reads complete
    st_cast16(&As[r0][c0], a0[0], a0[1], a0[2], a0[3]);
    st_cast16(&As[r0 + 64][c0], a1[0], a1[1], a1[2], a1[3]);
    *(uint4*)&Bs[r0][c0] = b00;       *(uint4*)&Bs[r0][c0 + 8] = b01;
    *(uint4*)&Bs[r0 + 64][c0] = b10;  *(uint4*)&Bs[r0 + 64][c0 + 8] = b11;
    __syncthreads();  // LDS tile ready
    if (kc + 64 < Kd) {  // prefetch next tile: latency hidden behind MFMAs
#pragma unroll
      for (int j = 0; j < 4; ++j) {
        a0[j] = ((const float4*)(gA0 + kc + 64))[j];
        a1[j] = ((const float4*)(gA1 + kc + 64))[j];
      }
      b00 = *(const uint4*)(gB0 + kc + 64);
      b01 = *(const uint4*)(gB0 + kc + 72);
      b10 = *(const uint4*)(gB1 + kc + 64);
      b11 = *(const uint4*)(gB1 + kc + 72);
    }
#pragma unroll
    for (int kst = 0; kst < 2; ++kst) {
      bf16x8 af[4], bfr[4];
#pragma unroll
      for (int i = 0; i < 4; ++i) {
        af[i] = *(const bf16x8*)&As[wm + i * 16 + ln][kst * 32 + qd * 8];
        bfr[i] = *(const bf16x8*)&Bs[wn + i * 16 + ln][kst * 32 + qd * 8];
      }
#pragma unroll
      for (int i = 0; i < 4; ++i)
#pragma unroll
        for (int j = 0; j < 4; ++j) {
          if (MODE == 1)
            acc[i][j] = mfma32(af[i], bfr[j], acc[i][j]);  // tok->(qd,rg)
          else
            acc[i][j] = mfma32(bfr[j], af[i], acc[i][j]);  // e->(qd,rg)
        }
    }
  }

#pragma unroll
  for (int i = 0; i < 4; ++i)
#pragma unroll
    for (int j = 0; j < 4; ++j) {
      if (MODE == 0) {
        const int gm = m0 + wm + i * 16 + ln;           // token
        const int gn0 = n0 + wn + j * 16 + qd * 4;      // e (4 consecutive)
        const int bb = gm >> 11, tok = gm & 2047;
        const int hh = gn0 >> 6, dd0 = gn0 & 63;
        bf16x4 v;
#pragma unroll
        for (int rg = 0; rg < 4; ++rg) v[rg] = (__bf16)(acc[i][j][rg] * scale);
        *(bf16x4*)(Cout + (((size_t)bb * 8 + hh) * 2048 + tok) * 64 + dd0) = v;
      } else {
        const int gm0 = m0 + wm + i * 16 + qd * 4;      // token (4 consecutive)
        const int gn = n0 + wn + j * 16 + ln;           // e
        const int bb = gm0 >> 11, tok0 = gm0 & 2047;
        const int hh = gn >> 6, dd = gn & 63;
        bf16x4 v;
#pragma unroll
        for (int rg = 0; rg < 4; ++rg) v[rg] = (__bf16)acc[i][j][rg];
        *(bf16x4*)(Cout + (((size_t)bb * 8 + hh) * 64 + dd) * 2048 + tok0) = v;
      }
    }
}

// Fused Q/K/V projections: grid (64, 12) = 768 blocks -> 3 blocks/CU.
__global__ __launch_bounds__(256, 3) void proj_qkv(
    const float* __restrict__ x, const float* __restrict__ ctx,
    const __bf16* __restrict__ Wq, const __bf16* __restrict__ Wk,
    const __bf16* __restrict__ Wv, __bf16* __restrict__ Qw,
    __bf16* __restrict__ Kw, __bf16* __restrict__ Vtw) {
  __shared__ __align__(16) __bf16 As[128][72];  // 18432B
  __shared__ __align__(16) __bf16 Bs[128][72];  // 18432B -> 36.9KB
  const int m0 = blockIdx.x * 128;
  const int job = blockIdx.y >> 2;  // 0=Q, 1=K, 2=V
  const int n0 = (blockIdx.y & 3) * 128;
  if (job == 0)
    gemm_body<0>(x, Wq, Qw, 512, QSCALE, m0, n0, As, Bs);
  else if (job == 1)
    gemm_body<0>(ctx, Wk, Kw, 768, 1.0f, m0, n0, As, Bs);
  else
    gemm_body<1>(ctx, Wv, Vtw, 768, 1.0f, m0, n0, As, Bs);
}

// ---------------------------------------------------------------------------
// Final GEMM: out = ((O0+O1)/(l0+l1)) Wo^T + bo, fp32.  64x128 tile, BK=64,
// register-prefetch pipeline, grid (128,4)=512.  inv(l) hoisted.
// ---------------------------------------------------------------------------
__global__ __launch_bounds__(256) void gemm_out(
    const __bf16* __restrict__ O0, const __bf16* __restrict__ O1,
    const float* __restrict__ lbuf,  // [2][32][2048]
    const __bf16* __restrict__ B,    // Wo bf16 [512 x 512]
    float* __restrict__ C, const float* __restrict__ bias) {
  const int m0 = blockIdx.x * 64;
  const int n0 = blockIdx.y * 128;
  const int t = threadIdx.x;
  const int w = t >> 6;
  const int lane = t & 63;
  const int ln = lane & 15;
  const int qd = lane >> 4;
  const int wm = (w >> 1) * 32;
  const int wn = (w & 1) * 64;

  __shared__ __align__(16) __bf16 As[64][72];   //  9216B
  __shared__ __align__(16) __bf16 Bs[128][72];  // 18432B -> 27.6KB

  f32x4 zero4 = {0.f, 0.f, 0.f, 0.f};
  f32x4 acc[2][4];
#pragma unroll
  for (int i = 0; i < 2; ++i)
#pragma unroll
    for (int j = 0; j < 4; ++j) acc[i][j] = zero4;

  const int r0 = t >> 2;        // 0..63
  const int c0 = (t & 3) * 16;  // 0/16/32/48
  const int gm_s = m0 + r0;
  const int bidx = gm_s >> 11, tok_s = gm_s & 2047;
  const size_t aoff = (size_t)gm_s * 512 + c0;
  const __bf16* gB0 = B + (size_t)(n0 + r0) * 512 + c0;
  const __bf16* gB1 = B + (size_t)(n0 + r0 + 64) * 512 + c0;

  float inv[8];
#pragma unroll
  for (int hh = 0; hh < 8; ++hh) {
    const float l0 = lbuf[((size_t)bidx * 8 + hh) * 2048 + tok_s];
    const float l1 = lbuf[65536 + ((size_t)bidx * 8 + hh) * 2048 + tok_s];
    inv[hh] = 1.0f / (l0 + l1);
  }

  // prologue: load tile 0
  uint4 o00 = *(const uint4*)(O0 + aoff), o01 = *(const uint4*)(O0 + aoff + 8);
  uint4 o10 = *(const uint4*)(O1 + aoff), o11 = *(const uint4*)(O1 + aoff + 8);
  uint4 b00 = *(const uint4*)gB0, b01 = *(const uint4*)(gB0 + 8);
  uint4 b10 = *(const uint4*)gB1, b11 = *(const uint4*)(gB1 + 8);

  for (int kc = 0; kc < 512; kc += 64) {
    const float iv = inv[kc >> 6];
    union { bf16x8 v; uint4 u; } u0, u1, r0v, r1v;
    u0.u = o00; u1.u = o10;
#pragma unroll
    for (int e = 0; e < 8; ++e)
      r0v.v[e] = (__bf16)(((float)u0.v[e] + (float)u1.v[e]) * iv);
    u0.u = o01; u1.u = o11;
#pragma unroll
    for (int e = 0; e < 8; ++e)
      r1v.v[e] = (__bf16)(((float)u0.v[e] + (float)u1.v[e]) * iv);
    __syncthreads();
    *(uint4*)&As[r0][c0] = r0v.u;
    *(uint4*)&As[r0][c0 + 8] = r1v.u;
    *(uint4*)&Bs[r0][c0] = b00;       *(uint4*)&Bs[r0][c0 + 8] = b01;
    *(uint4*)&Bs[r0 + 64][c0] = b10;  *(uint4*)&Bs[r0 + 64][c0 + 8] = b11;
    __syncthreads();
    if (kc + 64 < 512) {
      o00 = *(const uint4*)(O0 + aoff + kc + 64);
      o01 = *(const uint4*)(O0 + aoff + kc + 72);
      o10 = *(const uint4*)(O1 + aoff + kc + 64);
      o11 = *(const uint4*)(O1 + aoff + kc + 72);
      b00 = *(const uint4*)(gB0 + kc + 64);
      b01 = *(const uint4*)(gB0 + kc + 72);
      b10 = *(const uint4*)(gB1 + kc + 64);
      b11 = *(const uint4*)(gB1 + kc + 72);
    }
#pragma unroll
    for (int kst = 0; kst < 2; ++kst) {
      bf16x8 af[2], bfr[4];
#pragma unroll
      for (int i = 0; i < 2; ++i)
        af[i] = *(const bf16x8*)&As[wm + i * 16 + ln][kst * 32 + qd * 8];
#pragma unroll
      for (int j = 0; j < 4; ++j)
        bfr[j] = *(const bf16x8*)&Bs[wn + j * 16 + ln][kst * 32 + qd * 8];
#pragma unroll
      for (int i = 0; i < 2; ++i)
#pragma unroll
        for (int j = 0; j < 4; ++j)
          acc[i][j] = mfma32(bfr[j], af[i], acc[i][j]);  // e->(qd,rg)
    }
  }

#pragma unroll
  for (int i = 0; i < 2; ++i)
#pragma unroll
    for (int j = 0; j < 4; ++j) {
      const int gm = m0 + wm + i * 16 + ln;
      const int gn0 = n0 + wn + j * 16 + qd * 4;
      f32x4 bi = *(const f32x4*)&bias[gn0];
      f32x4 v = acc[i][j] + bi;
      *(f32x4*)&C[(size_t)gm * 512 + gn0] = v;
    }
}

// ---------------------------------------------------------------------------
// Flash attention, 32x32x16 MFMA (R25) + T15 double-pipeline (R26).
// S^T trick, raw-exp2 max-free softmax, split-K=2. 4 waves x 64 Q rows
// (2 q-groups of 32), KVBLK=128. sigma = swap bits 2<->3 of K-token row
// within each 32-group: QK output regs directly usable as PV B-frags.
// l = VALU row-sum (+shfl_xor(32) at epilogue). Dbuf single-barrier
// pipeline, reg prefetch 1 tile ahead, setprio. Grid (8,32,2).
// R26: two live S-states — QK(g+1) MFMA chains issue under exp2/pack(g)
// VALU work (T15, m214v36 +7-11%). Fully-unrolled g-loop, named states.
// ---------------------------------------------------------------------------
__global__ __launch_bounds__(256, 2) void attn_kernel(
    const __bf16* __restrict__ Q,   // [BH][2048][64], pre-scaled by QSCALE
    const __bf16* __restrict__ K,   // [BH][2048][64]
    const __bf16* __restrict__ Vt,  // [BH][64][2048]
    __bf16* __restrict__ Oh,        // [2][B][2048][512] unnormalized
    float* __restrict__ lbuf) {     // [2][BH][2048]
  const int S = 2048;
  const int qt = blockIdx.x;  // 8 Q tiles of 256 rows
  const int bh = blockIdx.y;
  const int sp = blockIdx.z;
  const int b = bh >> 3, h = bh & 7;
  const int t = threadIdx.x;
  const int w = t >> 6;        // 0..3: wave owns Q rows qt*256 + w*64 ..
  const int lane = t & 63;
  const int ln5 = lane & 31;
  const int hi = lane >> 5;

  __shared__ __align__(16) __bf16 Ks[2][128][72];   // 36864B
  __shared__ __align__(16) __bf16 Vs[2][64][136];   // 34816B  total 71680B

  const int qbase = qt * 256 + w * 64;

  // Q B-frags: bq[mt][ks], B[n=q=ln5][k=hi*8+j] at Q[qrow][ks*16 + hi*8]
  bf16x8 bq[2][4];
  {
    const __bf16* qb = Q + ((size_t)bh * S + qbase + ln5) * 64 + hi * 8;
#pragma unroll
    for (int mt = 0; mt < 2; ++mt)
#pragma unroll
      for (int ks = 0; ks < 4; ++ks)
        bq[mt][ks] = *(const bf16x8*)(qb + mt * 32 * 64 + ks * 16);
  }

  f32x16 zero16 = {0.f, 0.f, 0.f, 0.f, 0.f, 0.f, 0.f, 0.f,
                   0.f, 0.f, 0.f, 0.f, 0.f, 0.f, 0.f, 0.f};
  f32x16 oacc[2][2];  // [mt][d-half]: O^T[d][q]
#pragma unroll
  for (int mt = 0; mt < 2; ++mt)
#pragma unroll
    for (int dh = 0; dh < 2; ++dh) oacc[mt][dh] = zero16;
  float l_acc[2] = {0.f, 0.f};

  // K staging (256 threads): token row kr = t>>2 (0..63) and kr+64, 16 cols
  const int kr = t >> 2, kc0 = (t & 3) * 16;
  // sigma: swap bits 2<->3 of the token index within its 32-group
  const int krow = (kr & ~12) | ((kr & 4) << 1) | ((kr & 8) >> 1);
  // V staging: d-row vd = t>>3 (0..31) and vd+32, 16 tokens each
  const int vd = t >> 3, vtok0 = (t & 7) * 16;
  const int kt0 = sp * 8;

  const __bf16* gK0 = K + ((size_t)bh * S + kt0 * 128 + kr) * 64 + kc0;
  const __bf16* gK1 = gK0 + 4096;   // row kr+64
  const __bf16* gV0 = Vt + ((size_t)bh * 64 + vd) * S + kt0 * 128 + vtok0;
  const __bf16* gV1 = gV0 + 65536;  // row vd+32

  // prologue: tile 0 -> LDS buf 0; prefetch tile 1 into regs; one barrier.
  {
    uint4 k00 = ((const uint4*)gK0)[0], k01 = ((const uint4*)gK0)[1];
    uint4 k10 = ((const uint4*)gK1)[0], k11 = ((const uint4*)gK1)[1];
    uint4 v00 = ((const uint4*)gV0)[0], v01 = ((const uint4*)gV0)[1];
    uint4 v10 = ((const uint4*)gV1)[0], v11 = ((const uint4*)gV1)[1];
    uint4* dK0 = (uint4*)&Ks[0][krow][kc0];      dK0[0] = k00; dK0[1] = k01;
    uint4* dK1 = (uint4*)&Ks[0][krow + 64][kc0]; dK1[0] = k10; dK1[1] = k11;
    uint4* dV0 = (uint4*)&Vs[0][vd][vtok0];      dV0[0] = v00; dV0[1] = v01;
    uint4* dV1 = (uint4*)&Vs[0][vd + 32][vtok0]; dV1[0] = v10; dV1[1] = v11;
  }
  uint4 pk00 = ((const uint4*)(gK0 + 8192))[0];
  uint4 pk01 = ((const uint4*)(gK0 + 8192))[1];
  uint4 pk10 = ((const uint4*)(gK1 + 8192))[0];
  uint4 pk11 = ((const uint4*)(gK1 + 8192))[1];
  uint4 pv00 = ((const uint4*)(gV0 + 128))[0];
  uint4 pv01 = ((const uint4*)(gV0 + 128))[1];
  uint4 pv10 = ((const uint4*)(gV1 + 128))[0];
  uint4 pv11 = ((const uint4*)(gV1 + 128))[1];
  __syncthreads();

  int p = 0;
  for (int it = 0; it < 8; ++it) {
    if (it + 1 < 8) {  // stage tile it+1 into buf[p^1]; prefetch it+2
      uint4* dK0 = (uint4*)&Ks[p ^ 1][krow][kc0];
      dK0[0] = pk00; dK0[1] = pk01;
      uint4* dK1 = (uint4*)&Ks[p ^ 1][krow + 64][kc0];
      dK1[0] = pk10; dK1[1] = pk11;
      uint4* dV0 = (uint4*)&Vs[p ^ 1][vd][vtok0];
      dV0[0] = pv00; dV0[1] = pv01;
      uint4* dV1 = (uint4*)&Vs[p ^ 1][vd + 32][vtok0];
      dV1[0] = pv10; dV1[1] = pv11;
      if (it + 2 < 8) {
        const __bf16* nK0 = gK0 + (size_t)(it + 2) * 8192;
        const __bf16* nK1 = gK1 + (size_t)(it + 2) * 8192;
        const __bf16* nV0 = gV0 + (size_t)(it + 2) * 128;
        const __bf16* nV1 = gV1 + (size_t)(it + 2) * 128;
        pk00 = ((const uint4*)nK0)[0]; pk01 = ((const uint4*)nK0)[1];
        pk10 = ((const uint4*)nK1)[0]; pk11 = ((const uint4*)nK1)[1];
        pv00 = ((const uint4*)nV0)[0]; pv01 = ((const uint4*)nV0)[1];
        pv10 = ((const uint4*)nV1)[0]; pv11 = ((const uint4*)nV1)[1];
      }
    }

    const __bf16 (*Ksp)[72] = Ks[p];
    const __bf16 (*Vsp)[136] = Vs[p];

    // ---- T15 prologue: frags(0) + QK(0) for both mt -> sA state
    f32x16 sA0, sA1;
    {
      bf16x8 kf[4];
#pragma unroll
      for (int ks = 0; ks < 4; ++ks)
        kf[ks] = *(const bf16x8*)&Ksp[ln5][ks * 16 + hi * 8];
      sA0 = zero16; sA1 = zero16;
      __builtin_amdgcn_s_setprio(1);
#pragma unroll
      for (int ks = 0; ks < 4; ++ks) {
        sA0 = mfma3216(kf[ks], bq[0][ks], sA0);
        sA1 = mfma3216(kf[ks], bq[1][ks], sA1);
      }
      __builtin_amdgcn_s_setprio(0);
    }

#pragma unroll
    for (int g = 0; g < 4; ++g) {
      // next-group K frags (ds_reads issue; latency covered by exp2 below)
      bf16x8 kfB[4];
      if (g < 3) {
#pragma unroll
        for (int ks = 0; ks < 4; ++ks)
          kfB[ks] = *(const bf16x8*)&Ksp[(g + 1) * 32 + ln5][ks * 16 + hi * 8];
      }
      // exp2 + l row-sum for sA0 (VALU/trans — covers kfB ds_read latency)
      float la0 = 0.f;
#pragma unroll
      for (int r = 0; r < 16; ++r) {
        sA0[r] = EXP2(sA0[r]);
        la0 += sA0[r];
      }
      l_acc[0] += la0;
      // QK(g+1) for both mt into sB state (MFMA pipe)
      f32x16 sB0, sB1;
      if (g < 3) {
        sB0 = zero16; sB1 = zero16;
        __builtin_amdgcn_s_setprio(1);
#pragma unroll
        for (int ks = 0; ks < 4; ++ks) {
          sB0 = mfma3216(kfB[ks], bq[0][ks], sB0);
          sB1 = mfma3216(kfB[ks], bq[1][ks], sB1);
        }
        __builtin_amdgcn_s_setprio(0);
      }
      // V frags for group g (just-in-time)
      bf16x8 vf[2][2];  // [sub][dh]
#pragma unroll
      for (int sub = 0; sub < 2; ++sub)
#pragma unroll
        for (int dh = 0; dh < 2; ++dh)
          vf[sub][dh] = *(const bf16x8*)
              &Vsp[dh * 32 + ln5][g * 32 + sub * 16 + hi * 8];
      // pack + PV for mt0 (MFMA overlaps the exp2(sA1) below)
      {
        bf16x8 p0, p1;
#pragma unroll
        for (int j = 0; j < 8; ++j) {
          p0[j] = (__bf16)sA0[j];
          p1[j] = (__bf16)sA0[j + 8];
        }
        __builtin_amdgcn_s_setprio(1);
        oacc[0][0] = mfma3216(vf[0][0], p0, oacc[0][0]);
        oacc[0][1] = mfma3216(vf[0][1], p0, oacc[0][1]);
        oacc[0][0] = mfma3216(vf[1][0], p1, oacc[0][0]);
        oacc[0][1] = mfma3216(vf[1][1], p1, oacc[0][1]);
        __builtin_amdgcn_s_setprio(0);
      }
      // exp2 + l + pack + PV for mt1 (VALU first, then MFMA)
      {
        float la1 = 0.f;
#pragma unroll
        for (int r = 0; r < 16; ++r) {
          sA1[r] = EXP2(sA1[r]);
          la1 += sA1[r];
        }
        l_acc[1] += la1;
        bf16x8 p0, p1;
#pragma unroll
        for (int j = 0; j < 8; ++j) {
          p0[j] = (__bf16)sA1[j];
          p1[j] = (__bf16)sA1[j + 8];
        }
        __builtin_amdgcn_s_setprio(1);
        oacc[1][0] = mfma3216(vf[0][0], p0, oacc[1][0]);
        oacc[1][1] = mfma3216(vf[0][1], p0, oacc[1][1]);
        oacc[1][0] = mfma3216(vf[1][0], p1, oacc[1][0]);
        oacc[1][1] = mfma3216(vf[1][1], p1, oacc[1][1]);
        __builtin_amdgcn_s_setprio(0);
      }
      // rotate pipeline state (g-loop fully unrolled -> pure renaming)
      if (g < 3) {
        sA0 = sB0;
        sA1 = sB1;
      }
    }

    __syncthreads();  // buf[p^1] fully staged; buf[p] reads complete
    p ^= 1;
  }

  // ---- epilogue: write UNNORMALIZED O^T + l (combine in gemm_out)
  __bf16* Osp = Oh + (size_t)sp * 8192 * 512;
#pragma unroll
  for (int mt = 0; mt < 2; ++mt) {
    // l: lane(q,hi=0) has tokens {0-7,16-23}+32k, hi=1 the rest — combine.
    float l = l_acc[mt] + __shfl_xor(l_acc[mt], 32, 64);
    const int tok = qbase + mt * 32 + ln5;
    if (hi == 0) lbuf[((size_t)sp * 32 + bh) * 2048 + tok] = l;
    // O^T[d][q]: lane col q=ln5; rows d = (rg&3) + 8*(rg>>2) + 4*hi + 32*dh
#pragma unroll
    for (int dh = 0; dh < 2; ++dh)
#pragma unroll
      for (int rgg = 0; rgg < 4; ++rgg) {
        bf16x4 v;
#pragma unroll
        for (int e = 0; e < 4; ++e) v[e] = (__bf16)oacc[mt][dh][rgg * 4 + e];
        const int d0 = dh * 32 + 4 * hi + 8 * rgg;
        *(bf16x4*)&Osp[((size_t)b * S + tok) * 512 + h * 64 + d0] = v;
      }
  }
}

// ---------------------------------------------------------------------------
extern "C" void kernel_launch(void* const* d_in, const int* in_sizes, int n_in,
                              void* d_out, int out_size, void* d_ws,
                              size_t ws_size, hipStream_t stream) {
  const float* x = (const float*)d_in[0];
  const float* ctx = (const float*)d_in[1];
  const float* Wq = (const float*)d_in[2];
  const float* Wk = (const float*)d_in[3];
  const float* Wv = (const float*)d_in[4];
  const float* Wo = (const float*)d_in[5];
  const float* bo = (const float*)d_in[6];

  char* p = (char*)d_ws;
  __bf16* wqb = (__bf16*)p;  p += (size_t)512 * 512 * 2;
  __bf16* wkb = (__bf16*)p;  p += (size_t)512 * 768 * 2;
  __bf16* wvb = (__bf16*)p;  p += (size_t)512 * 768 * 2;
  __bf16* wob = (__bf16*)p;  p += (size_t)512 * 512 * 2;
  __bf16* Qw = (__bf16*)p;   p += (size_t)8192 * 512 * 2;
  __bf16* Kw = (__bf16*)p;   p += (size_t)8192 * 512 * 2;
  __bf16* Vtw = (__bf16*)p;  p += (size_t)8192 * 512 * 2;
  __bf16* Oh = (__bf16*)p;   p += (size_t)2 * 8192 * 512 * 2;
  float* lbuf = (float*)p;   p += (size_t)2 * 32 * 2048 * 4;

  cast_w<<<1280, 256, 0, stream>>>(Wq, Wk, Wv, Wo, wqb, wkb, wvb, wob);

  dim3 gp(64, 12);
  proj_qkv<<<gp, 256, 0, stream>>>(x, ctx, wqb, wkb, wvb, Qw, Kw, Vtw);

  dim3 ga(8, 32, 2);
  attn_kernel<<<ga, 256, 0, stream>>>(Qw, Kw, Vtw, Oh, lbuf);

  dim3 go(128, 4);
  gemm_out<<<go, 256, 0, stream>>>(Oh, Oh + (size_t)8192 * 512, lbuf, wob,
                                   (float*)d_out, bo);
}

// Round 12
// 173.473 us; speedup vs baseline: 1.0722x; 1.0722x over previous
//
#include <hip/hip_runtime.h>
#include <hip/hip_bf16.h>
#include <math.h>

// ---------------------------------------------------------------------------
// CrossAttention on MI355X (gfx950), bf16 MFMA pipeline, round 27.
// REVERT-TO-BEST: exact round-5 configuration (172.06us, session minimum).
//   cast_all: fp32 -> bf16 (BW-bound pass)  [R24 cast-fusion was net-zero:
//             proj's doubled fp32 A-traffic ate the cast savings]
//   proj_qkv: 128x128, BK=64, bf16 reg-staged (R12/R14)
//   attn: R19 form (best measured): 4 waves x 64 Q rows, KVBLK=128,
//         split-K=2, dbuf single-barrier, reg prefetch, per-mt body,
//         setprio. Seven later variants (phase-batch, split-K=4, 32x32
//         shape, T15) all measured equal-or-worse; cross-run noise +-6us.
//   gemm_out: 64x128, BK=64, 2-slab combine in staging, inv hoisted.
// ---------------------------------------------------------------------------

typedef __bf16 bf16x8 __attribute__((ext_vector_type(8)));
typedef __bf16 bf16x4 __attribute__((ext_vector_type(4)));
typedef float f32x4 __attribute__((ext_vector_type(4)));

#define QSCALE 0.18033688011112042f  // 0.125 * log2(e)

#if __has_builtin(__builtin_amdgcn_exp2f)
#define EXP2(x) __builtin_amdgcn_exp2f(x)
#else
#define EXP2(x) exp2f(x)
#endif

__device__ __forceinline__ f32x4 mfma32(bf16x8 a, bf16x8 b, f32x4 c) {
  // 16x16x32: A[m=ln][k=qd*8+j], B[n=ln][k=qd*8+j].
  // D: A's m -> (qd*4+rg), B's n -> ln.
  return __builtin_amdgcn_mfma_f32_16x16x32_bf16(a, b, c, 0, 0, 0);
}

// ---------------------------------------------------------------------------
// fp32 -> bf16 cast of all inputs.
// ---------------------------------------------------------------------------
__global__ __launch_bounds__(256) void cast_all(
    const float* __restrict__ x, const float* __restrict__ ctx,
    const float* __restrict__ wq, const float* __restrict__ wk,
    const float* __restrict__ wv, const float* __restrict__ wo,
    __bf16* __restrict__ xb, __bf16* __restrict__ cb,
    __bf16* __restrict__ wqb, __bf16* __restrict__ wkb,
    __bf16* __restrict__ wvb, __bf16* __restrict__ wob) {
  const int B0 = 1048576;
  const int B1 = 2621440;
  const int B2 = 2686976;
  const int B3 = 2785280;
  const int B4 = 2883584;
  const int B5 = 2949120;
  for (int i = blockIdx.x * blockDim.x + threadIdx.x; i < B5;
       i += gridDim.x * blockDim.x) {
    const float* s;
    __bf16* d;
    int off;
    if (i < B0)      { s = x;   d = xb;  off = i; }
    else if (i < B1) { s = ctx; d = cb;  off = i - B0; }
    else if (i < B2) { s = wq;  d = wqb; off = i - B1; }
    else if (i < B3) { s = wk;  d = wkb; off = i - B2; }
    else if (i < B4) { s = wv;  d = wvb; off = i - B3; }
    else             { s = wo;  d = wob; off = i - B4; }
    float4 f = ((const float4*)s)[off];
    union { __bf16 b[4]; ushort4 u; } cv;
    cv.b[0] = (__bf16)f.x; cv.b[1] = (__bf16)f.y;
    cv.b[2] = (__bf16)f.z; cv.b[3] = (__bf16)f.w;
    ((ushort4*)d)[off] = cv.u;
  }
}

// ---------------------------------------------------------------------------
// 128x128 GEMM body, BK=64, register-prefetch pipeline, coalesced staging.
// MODE 0 (roles swapped): bf16 out [b,h,tok,d], 8B stores over d
// MODE 1 (natural roles): bf16 out [b,h,d,tok], 8B stores over tok
// ---------------------------------------------------------------------------
template <int MODE>
__device__ __forceinline__ void gemm_body(
    const __bf16* __restrict__ A, const __bf16* __restrict__ W,
    __bf16* __restrict__ Cout, int Kd, float scale, int m0, int n0,
    __bf16 (*As)[72], __bf16 (*Bs)[72]) {
  const int t = threadIdx.x;
  const int w = t >> 6;
  const int lane = t & 63;
  const int ln = lane & 15;
  const int qd = lane >> 4;
  const int wm = (w >> 1) * 64;
  const int wn = (w & 1) * 64;

  f32x4 zero4 = {0.f, 0.f, 0.f, 0.f};
  f32x4 acc[4][4];
#pragma unroll
  for (int i = 0; i < 4; ++i)
#pragma unroll
    for (int j = 0; j < 4; ++j) acc[i][j] = zero4;

  const int r0 = t >> 2;          // 0..63
  const int c0 = (t & 3) * 16;    // 0/16/32/48
  const __bf16* gA0 = A + (size_t)(m0 + r0) * Kd + c0;
  const __bf16* gA1 = A + (size_t)(m0 + r0 + 64) * Kd + c0;
  const __bf16* gB0 = W + (size_t)(n0 + r0) * Kd + c0;
  const __bf16* gB1 = W + (size_t)(n0 + r0 + 64) * Kd + c0;

  // prologue: load tile 0 into registers
  uint4 a00 = *(const uint4*)gA0, a01 = *(const uint4*)(gA0 + 8);
  uint4 a10 = *(const uint4*)gA1, a11 = *(const uint4*)(gA1 + 8);
  uint4 b00 = *(const uint4*)gB0, b01 = *(const uint4*)(gB0 + 8);
  uint4 b10 = *(const uint4*)gB1, b11 = *(const uint4*)(gB1 + 8);

  for (int kc = 0; kc < Kd; kc += 64) {
    __syncthreads();  // previous iteration's frag reads complete
    *(uint4*)&As[r0][c0] = a00;       *(uint4*)&As[r0][c0 + 8] = a01;
    *(uint4*)&As[r0 + 64][c0] = a10;  *(uint4*)&As[r0 + 64][c0 + 8] = a11;
    *(uint4*)&Bs[r0][c0] = b00;       *(uint4*)&Bs[r0][c0 + 8] = b01;
    *(uint4*)&Bs[r0 + 64][c0] = b10;  *(uint4*)&Bs[r0 + 64][c0 + 8] = b11;
    __syncthreads();  // LDS tile ready
    if (kc + 64 < Kd) {  // prefetch next tile: latency hidden behind MFMAs
      a00 = *(const uint4*)(gA0 + kc + 64);
      a01 = *(const uint4*)(gA0 + kc + 72);
      a10 = *(const uint4*)(gA1 + kc + 64);
      a11 = *(const uint4*)(gA1 + kc + 72);
      b00 = *(const uint4*)(gB0 + kc + 64);
      b01 = *(const uint4*)(gB0 + kc + 72);
      b10 = *(const uint4*)(gB1 + kc + 64);
      b11 = *(const uint4*)(gB1 + kc + 72);
    }
#pragma unroll
    for (int kst = 0; kst < 2; ++kst) {
      bf16x8 af[4], bfr[4];
#pragma unroll
      for (int i = 0; i < 4; ++i) {
        af[i] = *(const bf16x8*)&As[wm + i * 16 + ln][kst * 32 + qd * 8];
        bfr[i] = *(const bf16x8*)&Bs[wn + i * 16 + ln][kst * 32 + qd * 8];
      }
#pragma unroll
      for (int i = 0; i < 4; ++i)
#pragma unroll
        for (int j = 0; j < 4; ++j) {
          if (MODE == 1)
            acc[i][j] = mfma32(af[i], bfr[j], acc[i][j]);  // tok->(qd,rg)
          else
            acc[i][j] = mfma32(bfr[j], af[i], acc[i][j]);  // e->(qd,rg)
        }
    }
  }

#pragma unroll
  for (int i = 0; i < 4; ++i)
#pragma unroll
    for (int j = 0; j < 4; ++j) {
      if (MODE == 0) {
        const int gm = m0 + wm + i * 16 + ln;           // token
        const int gn0 = n0 + wn + j * 16 + qd * 4;      // e (4 consecutive)
        const int bb = gm >> 11, tok = gm & 2047;
        const int hh = gn0 >> 6, dd0 = gn0 & 63;
        bf16x4 v;
#pragma unroll
        for (int rg = 0; rg < 4; ++rg) v[rg] = (__bf16)(acc[i][j][rg] * scale);
        *(bf16x4*)(Cout + (((size_t)bb * 8 + hh) * 2048 + tok) * 64 + dd0) = v;
      } else {
        const int gm0 = m0 + wm + i * 16 + qd * 4;      // token (4 consecutive)
        const int gn = n0 + wn + j * 16 + ln;           // e
        const int bb = gm0 >> 11, tok0 = gm0 & 2047;
        const int hh = gn >> 6, dd = gn & 63;
        bf16x4 v;
#pragma unroll
        for (int rg = 0; rg < 4; ++rg) v[rg] = (__bf16)acc[i][j][rg];
        *(bf16x4*)(Cout + (((size_t)bb * 8 + hh) * 64 + dd) * 2048 + tok0) = v;
      }
    }
}

// Fused Q/K/V projections: grid (64, 12) = 768 blocks -> 3 blocks/CU.
__global__ __launch_bounds__(256, 3) void proj_qkv(
    const __bf16* __restrict__ xb, const __bf16* __restrict__ cb,
    const __bf16* __restrict__ Wq, const __bf16* __restrict__ Wk,
    const __bf16* __restrict__ Wv, __bf16* __restrict__ Qw,
    __bf16* __restrict__ Kw, __bf16* __restrict__ Vtw) {
  __shared__ __align__(16) __bf16 As[128][72];  // 18432B
  __shared__ __align__(16) __bf16 Bs[128][72];  // 18432B -> 36.9KB
  const int m0 = blockIdx.x * 128;
  const int job = blockIdx.y >> 2;  // 0=Q, 1=K, 2=V
  const int n0 = (blockIdx.y & 3) * 128;
  if (job == 0)
    gemm_body<0>(xb, Wq, Qw, 512, QSCALE, m0, n0, As, Bs);
  else if (job == 1)
    gemm_body<0>(cb, Wk, Kw, 768, 1.0f, m0, n0, As, Bs);
  else
    gemm_body<1>(cb, Wv, Vtw, 768, 1.0f, m0, n0, As, Bs);
}

// ---------------------------------------------------------------------------
// Final GEMM: out = ((O0+O1)/(l0+l1)) Wo^T + bo, fp32.  64x128 tile, BK=64,
// register-prefetch pipeline, grid (128,4)=512.  inv(l) hoisted.
// ---------------------------------------------------------------------------
__global__ __launch_bounds__(256) void gemm_out(
    const __bf16* __restrict__ O0, const __bf16* __restrict__ O1,
    const float* __restrict__ lbuf,  // [2][32][2048]
    const __bf16* __restrict__ B,    // Wo bf16 [512 x 512]
    float* __restrict__ C, const float* __restrict__ bias) {
  const int m0 = blockIdx.x * 64;
  const int n0 = blockIdx.y * 128;
  const int t = threadIdx.x;
  const int w = t >> 6;
  const int lane = t & 63;
  const int ln = lane & 15;
  const int qd = lane >> 4;
  const int wm = (w >> 1) * 32;
  const int wn = (w & 1) * 64;

  __shared__ __align__(16) __bf16 As[64][72];   //  9216B
  __shared__ __align__(16) __bf16 Bs[128][72];  // 18432B -> 27.6KB

  f32x4 zero4 = {0.f, 0.f, 0.f, 0.f};
  f32x4 acc[2][4];
#pragma unroll
  for (int i = 0; i < 2; ++i)
#pragma unroll
    for (int j = 0; j < 4; ++j) acc[i][j] = zero4;

  const int r0 = t >> 2;        // 0..63
  const int c0 = (t & 3) * 16;  // 0/16/32/48
  const int gm_s = m0 + r0;
  const int bidx = gm_s >> 11, tok_s = gm_s & 2047;
  const size_t aoff = (size_t)gm_s * 512 + c0;
  const __bf16* gB0 = B + (size_t)(n0 + r0) * 512 + c0;
  const __bf16* gB1 = B + (size_t)(n0 + r0 + 64) * 512 + c0;

  float inv[8];
#pragma unroll
  for (int hh = 0; hh < 8; ++hh) {
    const float l0 = lbuf[((size_t)bidx * 8 + hh) * 2048 + tok_s];
    const float l1 = lbuf[65536 + ((size_t)bidx * 8 + hh) * 2048 + tok_s];
    inv[hh] = 1.0f / (l0 + l1);
  }

  // prologue: load tile 0
  uint4 o00 = *(const uint4*)(O0 + aoff), o01 = *(const uint4*)(O0 + aoff + 8);
  uint4 o10 = *(const uint4*)(O1 + aoff), o11 = *(const uint4*)(O1 + aoff + 8);
  uint4 b00 = *(const uint4*)gB0, b01 = *(const uint4*)(gB0 + 8);
  uint4 b10 = *(const uint4*)gB1, b11 = *(const uint4*)(gB1 + 8);

  for (int kc = 0; kc < 512; kc += 64) {
    const float iv = inv[kc >> 6];
    union { bf16x8 v; uint4 u; } u0, u1, r0v, r1v;
    u0.u = o00; u1.u = o10;
#pragma unroll
    for (int e = 0; e < 8; ++e)
      r0v.v[e] = (__bf16)(((float)u0.v[e] + (float)u1.v[e]) * iv);
    u0.u = o01; u1.u = o11;
#pragma unroll
    for (int e = 0; e < 8; ++e)
      r1v.v[e] = (__bf16)(((float)u0.v[e] + (float)u1.v[e]) * iv);
    __syncthreads();
    *(uint4*)&As[r0][c0] = r0v.u;
    *(uint4*)&As[r0][c0 + 8] = r1v.u;
    *(uint4*)&Bs[r0][c0] = b00;       *(uint4*)&Bs[r0][c0 + 8] = b01;
    *(uint4*)&Bs[r0 + 64][c0] = b10;  *(uint4*)&Bs[r0 + 64][c0 + 8] = b11;
    __syncthreads();
    if (kc + 64 < 512) {
      o00 = *(const uint4*)(O0 + aoff + kc + 64);
      o01 = *(const uint4*)(O0 + aoff + kc + 72);
      o10 = *(const uint4*)(O1 + aoff + kc + 64);
      o11 = *(const uint4*)(O1 + aoff + kc + 72);
      b00 = *(const uint4*)(gB0 + kc + 64);
      b01 = *(const uint4*)(gB0 + kc + 72);
      b10 = *(const uint4*)(gB1 + kc + 64);
      b11 = *(const uint4*)(gB1 + kc + 72);
    }
#pragma unroll
    for (int kst = 0; kst < 2; ++kst) {
      bf16x8 af[2], bfr[4];
#pragma unroll
      for (int i = 0; i < 2; ++i)
        af[i] = *(const bf16x8*)&As[wm + i * 16 + ln][kst * 32 + qd * 8];
#pragma unroll
      for (int j = 0; j < 4; ++j)
        bfr[j] = *(const bf16x8*)&Bs[wn + j * 16 + ln][kst * 32 + qd * 8];
#pragma unroll
      for (int i = 0; i < 2; ++i)
#pragma unroll
        for (int j = 0; j < 4; ++j)
          acc[i][j] = mfma32(bfr[j], af[i], acc[i][j]);  // e->(qd,rg)
    }
  }

#pragma unroll
  for (int i = 0; i < 2; ++i)
#pragma unroll
    for (int j = 0; j < 4; ++j) {
      const int gm = m0 + wm + i * 16 + ln;
      const int gn0 = n0 + wn + j * 16 + qd * 4;
      f32x4 bi = *(const f32x4*)&bias[gn0];
      f32x4 v = acc[i][j] + bi;
      *(f32x4*)&C[(size_t)gm * 512 + gn0] = v;
    }
}

// ---------------------------------------------------------------------------
// Flash attention: S^T trick, raw-exp2 max-free softmax, Q in regs,
// sigma-permuted K rows -> x32 PV, ones-x32 l row-sum.
// R19 (best measured): 4 waves x 64 Q ROWS each (256-thread blocks,
// BQ=256), KVBLK=128, split-K=2, ak/av frags amortized over 4 mt, dbuf
// single-barrier pipeline, reg prefetch 1 tile ahead, setprio around MFMA
// clusters. Grid (8,32,2)=512 -> 2 blocks/CU, LDS 71.7KB x 2 = 143KB/CU.
// ---------------------------------------------------------------------------
__global__ __launch_bounds__(256, 2) void attn_kernel(
    const __bf16* __restrict__ Q,   // [BH][2048][64], pre-scaled by QSCALE
    const __bf16* __restrict__ K,   // [BH][2048][64]
    const __bf16* __restrict__ Vt,  // [BH][64][2048]
    __bf16* __restrict__ Oh,        // [2][B][2048][512] unnormalized
    float* __restrict__ lbuf) {     // [2][BH][2048]
  const int S = 2048;
  const int qt = blockIdx.x;  // 8 Q tiles of 256 rows
  const int bh = blockIdx.y;
  const int sp = blockIdx.z;
  const int b = bh >> 3, h = bh & 7;
  const int t = threadIdx.x;
  const int w = t >> 6;       // 0..3: wave owns Q rows qt*256 + w*64 ..
  const int lane = t & 63;
  const int ln = lane & 15;
  const int qd = lane >> 4;

  __shared__ __align__(16) __bf16 Ks[2][128][72];   // 36864B
  __shared__ __align__(16) __bf16 Vs[2][64][136];   // 34816B  total 71680B

  bf16x8 bq[4][2];  // [mt][kst] — 64 Q rows per wave
  {
    const __bf16* qb =
        Q + ((size_t)bh * S + qt * 256 + w * 64 + ln) * 64 + qd * 8;
#pragma unroll
    for (int mt = 0; mt < 4; ++mt)
#pragma unroll
      for (int kst = 0; kst < 2; ++kst)
        bq[mt][kst] = *(const bf16x8*)(qb + mt * 1024 + kst * 32);
  }

  f32x4 zero4 = {0.f, 0.f, 0.f, 0.f};
  f32x4 o[4][4];
  f32x4 o_l[4];
#pragma unroll
  for (int mt = 0; mt < 4; ++mt) {
#pragma unroll
    for (int i = 0; i < 4; ++i) o[mt][i] = zero4;
    o_l[mt] = zero4;
  }
  bf16x8 ones8;
  {
    union { unsigned short u[8]; bf16x8 v; } U;
#pragma unroll
    for (int e = 0; e < 8; ++e) U.u[e] = 0x3F80;  // bf16 1.0
    ones8 = U.v;
  }

  // K staging (256 threads): token row kr = t>>2 (0..63) and kr+64, 16 cols
  const int kr = t >> 2, kc0 = (t & 3) * 16;
  // sigma: token v -> row 16*((v>>2)&1) + 4*(v>>3) + (v&3) within 32-chunk
  const int krow =
      (kr & ~31) | ((kr & 4) << 2) | (((kr >> 3) & 3) << 2) | (kr & 3);
  // V staging: d-row vd = t>>3 (0..31) and vd+32, 16 tokens each
  const int vd = t >> 3, vtok0 = (t & 7) * 16;
  const int kt0 = sp * 8;

  // Hoisted global staging bases (advance by constants per tile).
  const __bf16* gK0 = K + ((size_t)bh * S + kt0 * 128 + kr) * 64 + kc0;
  const __bf16* gK1 = gK0 + 4096;   // row kr+64
  const __bf16* gV0 = Vt + ((size_t)bh * 64 + vd) * S + kt0 * 128 + vtok0;
  const __bf16* gV1 = gV0 + 65536;  // row vd+32

  // prologue: tile 0 -> LDS buf 0; prefetch tile 1 into regs; one barrier.
  {
    uint4 k00 = ((const uint4*)gK0)[0], k01 = ((const uint4*)gK0)[1];
    uint4 k10 = ((const uint4*)gK1)[0], k11 = ((const uint4*)gK1)[1];
    uint4 v00 = ((const uint4*)gV0)[0], v01 = ((const uint4*)gV0)[1];
    uint4 v10 = ((const uint4*)gV1)[0], v11 = ((const uint4*)gV1)[1];
    uint4* dK0 = (uint4*)&Ks[0][krow][kc0];      dK0[0] = k00; dK0[1] = k01;
    uint4* dK1 = (uint4*)&Ks[0][krow + 64][kc0]; dK1[0] = k10; dK1[1] = k11;
    uint4* dV0 = (uint4*)&Vs[0][vd][vtok0];      dV0[0] = v00; dV0[1] = v01;
    uint4* dV1 = (uint4*)&Vs[0][vd + 32][vtok0]; dV1[0] = v10; dV1[1] = v11;
  }
  uint4 pk00 = ((const uint4*)(gK0 + 8192))[0];
  uint4 pk01 = ((const uint4*)(gK0 + 8192))[1];
  uint4 pk10 = ((const uint4*)(gK1 + 8192))[0];
  uint4 pk11 = ((const uint4*)(gK1 + 8192))[1];
  uint4 pv00 = ((const uint4*)(gV0 + 128))[0];
  uint4 pv01 = ((const uint4*)(gV0 + 128))[1];
  uint4 pv10 = ((const uint4*)(gV1 + 128))[0];
  uint4 pv11 = ((const uint4*)(gV1 + 128))[1];
  __syncthreads();

  int p = 0;
  for (int it = 0; it < 8; ++it) {
    // stage tile it+1 into buf[p^1] (overlaps with compute on buf[p]);
    // issue global loads for tile it+2 (a full iteration of latency cover).
    if (it + 1 < 8) {
      uint4* dK0 = (uint4*)&Ks[p ^ 1][krow][kc0];
      dK0[0] = pk00; dK0[1] = pk01;
      uint4* dK1 = (uint4*)&Ks[p ^ 1][krow + 64][kc0];
      dK1[0] = pk10; dK1[1] = pk11;
      uint4* dV0 = (uint4*)&Vs[p ^ 1][vd][vtok0];
      dV0[0] = pv00; dV0[1] = pv01;
      uint4* dV1 = (uint4*)&Vs[p ^ 1][vd + 32][vtok0];
      dV1[0] = pv10; dV1[1] = pv11;
      if (it + 2 < 8) {
        const __bf16* nK0 = gK0 + (size_t)(it + 2) * 8192;
        const __bf16* nK1 = gK1 + (size_t)(it + 2) * 8192;
        const __bf16* nV0 = gV0 + (size_t)(it + 2) * 128;
        const __bf16* nV1 = gV1 + (size_t)(it + 2) * 128;
        pk00 = ((const uint4*)nK0)[0]; pk01 = ((const uint4*)nK0)[1];
        pk10 = ((const uint4*)nK1)[0]; pk11 = ((const uint4*)nK1)[1];
        pv00 = ((const uint4*)nV0)[0]; pv01 = ((const uint4*)nV0)[1];
        pv10 = ((const uint4*)nV1)[0]; pv11 = ((const uint4*)nV1)[1];
      }
    }

    const __bf16 (*Ksp)[72] = Ks[p];
    const __bf16 (*Vsp)[136] = Vs[p];

    // per 32-token chunk c: load ak/av frags ONCE, feed all 4 mt
#pragma unroll
    for (int c = 0; c < 4; ++c) {
      bf16x8 ak[2][2];  // [e][kst]
#pragma unroll
      for (int e = 0; e < 2; ++e)
#pragma unroll
        for (int kst = 0; kst < 2; ++kst)
          ak[e][kst] =
              *(const bf16x8*)&Ksp[(c * 2 + e) * 16 + ln][kst * 32 + qd * 8];
      bf16x8 av[4];
#pragma unroll
      for (int i = 0; i < 4; ++i)
        av[i] = *(const bf16x8*)&Vsp[i * 16 + ln][c * 32 + qd * 8];

#pragma unroll
      for (int mt = 0; mt < 4; ++mt) {
        f32x4 s0 = zero4, s1 = zero4;
        __builtin_amdgcn_s_setprio(1);
#pragma unroll
        for (int kst = 0; kst < 2; ++kst) {
          s0 = mfma32(ak[0][kst], bq[mt][kst], s0);
          s1 = mfma32(ak[1][kst], bq[mt][kst], s1);
        }
        __builtin_amdgcn_s_setprio(0);
#pragma unroll
        for (int rg = 0; rg < 4; ++rg) {
          s0[rg] = EXP2(s0[rg]);
          s1[rg] = EXP2(s1[rg]);
        }
        bf16x8 p2;  // P as x32 B-frag: lane holds tokens c*32 + qd*8 + j
#pragma unroll
        for (int rg = 0; rg < 4; ++rg) {
          p2[rg] = (__bf16)s0[rg];
          p2[rg + 4] = (__bf16)s1[rg];
        }
        __builtin_amdgcn_s_setprio(1);
        o_l[mt] = mfma32(ones8, p2, o_l[mt]);
#pragma unroll
        for (int i = 0; i < 4; ++i)
          o[mt][i] = mfma32(av[i], p2, o[mt][i]);
        __builtin_amdgcn_s_setprio(0);
      }
    }

    __syncthreads();  // buf[p^1] fully staged; buf[p] reads complete
    p ^= 1;
  }

  // ---- epilogue: write UNNORMALIZED O + l (combine happens in gemm_out)
  __bf16* Osp = Oh + (size_t)sp * 8192 * 512;
#pragma unroll
  for (int mt = 0; mt < 4; ++mt) {
    const int tok = qt * 256 + w * 64 + mt * 16 + ln;
    if (qd == 0) lbuf[((size_t)sp * 32 + bh) * 2048 + tok] = o_l[mt][0];
#pragma unroll
    for (int i = 0; i < 4; ++i) {
      bf16x4 v;
#pragma unroll
      for (int rg = 0; rg < 4; ++rg) v[rg] = (__bf16)o[mt][i][rg];
      const int col = h * 64 + i * 16 + qd * 4;
      *(bf16x4*)&Osp[((size_t)b * S + tok) * 512 + col] = v;
    }
  }
}

// ---------------------------------------------------------------------------
extern "C" void kernel_launch(void* const* d_in, const int* in_sizes, int n_in,
                              void* d_out, int out_size, void* d_ws,
                              size_t ws_size, hipStream_t stream) {
  const float* x = (const float*)d_in[0];
  const float* ctx = (const float*)d_in[1];
  const float* Wq = (const float*)d_in[2];
  const float* Wk = (const float*)d_in[3];
  const float* Wv = (const float*)d_in[4];
  const float* Wo = (const float*)d_in[5];
  const float* bo = (const float*)d_in[6];

  char* p = (char*)d_ws;
  __bf16* xb = (__bf16*)p;   p += (size_t)8192 * 512 * 2;
  __bf16* cb = (__bf16*)p;   p += (size_t)8192 * 768 * 2;
  __bf16* wqb = (__bf16*)p;  p += (size_t)512 * 512 * 2;
  __bf16* wkb = (__bf16*)p;  p += (size_t)512 * 768 * 2;
  __bf16* wvb = (__bf16*)p;  p += (size_t)512 * 768 * 2;
  __bf16* wob = (__bf16*)p;  p += (size_t)512 * 512 * 2;
  __bf16* Qw = (__bf16*)p;   p += (size_t)8192 * 512 * 2;
  __bf16* Kw = (__bf16*)p;   p += (size_t)8192 * 512 * 2;
  __bf16* Vtw = (__bf16*)p;  p += (size_t)8192 * 512 * 2;
  __bf16* Oh = (__bf16*)p;   p += (size_t)2 * 8192 * 512 * 2;
  float* lbuf = (float*)p;   p += (size_t)2 * 32 * 2048 * 4;

  cast_all<<<2880, 256, 0, stream>>>(x, ctx, Wq, Wk, Wv, Wo, xb, cb, wqb, wkb,
                                     wvb, wob);

  dim3 gp(64, 12);
  proj_qkv<<<gp, 256, 0, stream>>>(xb, cb, wqb, wkb, wvb, Qw, Kw, Vtw);

  dim3 ga(8, 32, 2);
  attn_kernel<<<ga, 256, 0, stream>>>(Qw, Kw, Vtw, Oh, lbuf);

  dim3 go(128, 4);
  gemm_out<<<go, 256, 0, stream>>>(Oh, Oh + (size_t)8192 * 512, lbuf, wob,
                                   (float*)d_out, bo);
}

// Round 14
// 170.827 us; speedup vs baseline: 1.0888x; 1.0155x over previous
//
#include <hip/hip_runtime.h>
#include <hip/hip_bf16.h>
#include <math.h>

// ---------------------------------------------------------------------------
// CrossAttention on MI355X (gfx950), bf16 MFMA pipeline, round 29
// (resubmission of R28 — GPUAcquisitionTimeout, never measured).
// R27 (= round-5 best, 172-173.5us reproducible) + T1 XCD-aware swizzle on
// attn: grid linearized 1D (512) with pair->XCD grouping so the 8 qt-blocks
// sharing one (bh,sp)'s K/V land on ONE XCD's L2 (was: 8 XCDs, 8x re-fetch;
// attn FETCH 71MB vs 25MB ideal). Bijective decode (nwg%8==0, m204 rule).
// All other kernels byte-identical to R27.
//   cast_all: fp32 -> bf16 (BW-bound pass)
//   proj_qkv: 128x128, BK=64, bf16 reg-staged (R12/R14)
//   attn: R19 form: 4 waves x 64 Q rows, KVBLK=128, split-K=2, dbuf
//         single-barrier, reg prefetch, per-mt body, setprio.
//   gemm_out: 64x128, BK=64, 2-slab combine in staging, inv hoisted.
// ---------------------------------------------------------------------------

typedef __bf16 bf16x8 __attribute__((ext_vector_type(8)));
typedef __bf16 bf16x4 __attribute__((ext_vector_type(4)));
typedef float f32x4 __attribute__((ext_vector_type(4)));

#define QSCALE 0.18033688011112042f  // 0.125 * log2(e)

#if __has_builtin(__builtin_amdgcn_exp2f)
#define EXP2(x) __builtin_amdgcn_exp2f(x)
#else
#define EXP2(x) exp2f(x)
#endif

__device__ __forceinline__ f32x4 mfma32(bf16x8 a, bf16x8 b, f32x4 c) {
  // 16x16x32: A[m=ln][k=qd*8+j], B[n=ln][k=qd*8+j].
  // D: A's m -> (qd*4+rg), B's n -> ln.
  return __builtin_amdgcn_mfma_f32_16x16x32_bf16(a, b, c, 0, 0, 0);
}

// ---------------------------------------------------------------------------
// fp32 -> bf16 cast of all inputs.
// ---------------------------------------------------------------------------
__global__ __launch_bounds__(256) void cast_all(
    const float* __restrict__ x, const float* __restrict__ ctx,
    const float* __restrict__ wq, const float* __restrict__ wk,
    const float* __restrict__ wv, const float* __restrict__ wo,
    __bf16* __restrict__ xb, __bf16* __restrict__ cb,
    __bf16* __restrict__ wqb, __bf16* __restrict__ wkb,
    __bf16* __restrict__ wvb, __bf16* __restrict__ wob) {
  const int B0 = 1048576;
  const int B1 = 2621440;
  const int B2 = 2686976;
  const int B3 = 2785280;
  const int B4 = 2883584;
  const int B5 = 2949120;
  for (int i = blockIdx.x * blockDim.x + threadIdx.x; i < B5;
       i += gridDim.x * blockDim.x) {
    const float* s;
    __bf16* d;
    int off;
    if (i < B0)      { s = x;   d = xb;  off = i; }
    else if (i < B1) { s = ctx; d = cb;  off = i - B0; }
    else if (i < B2) { s = wq;  d = wqb; off = i - B1; }
    else if (i < B3) { s = wk;  d = wkb; off = i - B2; }
    else if (i < B4) { s = wv;  d = wvb; off = i - B3; }
    else             { s = wo;  d = wob; off = i - B4; }
    float4 f = ((const float4*)s)[off];
    union { __bf16 b[4]; ushort4 u; } cv;
    cv.b[0] = (__bf16)f.x; cv.b[1] = (__bf16)f.y;
    cv.b[2] = (__bf16)f.z; cv.b[3] = (__bf16)f.w;
    ((ushort4*)d)[off] = cv.u;
  }
}

// ---------------------------------------------------------------------------
// 128x128 GEMM body, BK=64, register-prefetch pipeline, coalesced staging.
// MODE 0 (roles swapped): bf16 out [b,h,tok,d], 8B stores over d
// MODE 1 (natural roles): bf16 out [b,h,d,tok], 8B stores over tok
// ---------------------------------------------------------------------------
template <int MODE>
__device__ __forceinline__ void gemm_body(
    const __bf16* __restrict__ A, const __bf16* __restrict__ W,
    __bf16* __restrict__ Cout, int Kd, float scale, int m0, int n0,
    __bf16 (*As)[72], __bf16 (*Bs)[72]) {
  const int t = threadIdx.x;
  const int w = t >> 6;
  const int lane = t & 63;
  const int ln = lane & 15;
  const int qd = lane >> 4;
  const int wm = (w >> 1) * 64;
  const int wn = (w & 1) * 64;

  f32x4 zero4 = {0.f, 0.f, 0.f, 0.f};
  f32x4 acc[4][4];
#pragma unroll
  for (int i = 0; i < 4; ++i)
#pragma unroll
    for (int j = 0; j < 4; ++j) acc[i][j] = zero4;

  const int r0 = t >> 2;          // 0..63
  const int c0 = (t & 3) * 16;    // 0/16/32/48
  const __bf16* gA0 = A + (size_t)(m0 + r0) * Kd + c0;
  const __bf16* gA1 = A + (size_t)(m0 + r0 + 64) * Kd + c0;
  const __bf16* gB0 = W + (size_t)(n0 + r0) * Kd + c0;
  const __bf16* gB1 = W + (size_t)(n0 + r0 + 64) * Kd + c0;

  // prologue: load tile 0 into registers
  uint4 a00 = *(const uint4*)gA0, a01 = *(const uint4*)(gA0 + 8);
  uint4 a10 = *(const uint4*)gA1, a11 = *(const uint4*)(gA1 + 8);
  uint4 b00 = *(const uint4*)gB0, b01 = *(const uint4*)(gB0 + 8);
  uint4 b10 = *(const uint4*)gB1, b11 = *(const uint4*)(gB1 + 8);

  for (int kc = 0; kc < Kd; kc += 64) {
    __syncthreads();  // previous iteration's frag reads complete
    *(uint4*)&As[r0][c0] = a00;       *(uint4*)&As[r0][c0 + 8] = a01;
    *(uint4*)&As[r0 + 64][c0] = a10;  *(uint4*)&As[r0 + 64][c0 + 8] = a11;
    *(uint4*)&Bs[r0][c0] = b00;       *(uint4*)&Bs[r0][c0 + 8] = b01;
    *(uint4*)&Bs[r0 + 64][c0] = b10;  *(uint4*)&Bs[r0 + 64][c0 + 8] = b11;
    __syncthreads();  // LDS tile ready
    if (kc + 64 < Kd) {  // prefetch next tile: latency hidden behind MFMAs
      a00 = *(const uint4*)(gA0 + kc + 64);
      a01 = *(const uint4*)(gA0 + kc + 72);
      a10 = *(const uint4*)(gA1 + kc + 64);
      a11 = *(const uint4*)(gA1 + kc + 72);
      b00 = *(const uint4*)(gB0 + kc + 64);
      b01 = *(const uint4*)(gB0 + kc + 72);
      b10 = *(const uint4*)(gB1 + kc + 64);
      b11 = *(const uint4*)(gB1 + kc + 72);
    }
#pragma unroll
    for (int kst = 0; kst < 2; ++kst) {
      bf16x8 af[4], bfr[4];
#pragma unroll
      for (int i = 0; i < 4; ++i) {
        af[i] = *(const bf16x8*)&As[wm + i * 16 + ln][kst * 32 + qd * 8];
        bfr[i] = *(const bf16x8*)&Bs[wn + i * 16 + ln][kst * 32 + qd * 8];
      }
#pragma unroll
      for (int i = 0; i < 4; ++i)
#pragma unroll
        for (int j = 0; j < 4; ++j) {
          if (MODE == 1)
            acc[i][j] = mfma32(af[i], bfr[j], acc[i][j]);  // tok->(qd,rg)
          else
            acc[i][j] = mfma32(bfr[j], af[i], acc[i][j]);  // e->(qd,rg)
        }
    }
  }

#pragma unroll
  for (int i = 0; i < 4; ++i)
#pragma unroll
    for (int j = 0; j < 4; ++j) {
      if (MODE == 0) {
        const int gm = m0 + wm + i * 16 + ln;           // token
        const int gn0 = n0 + wn + j * 16 + qd * 4;      // e (4 consecutive)
        const int bb = gm >> 11, tok = gm & 2047;
        const int hh = gn0 >> 6, dd0 = gn0 & 63;
        bf16x4 v;
#pragma unroll
        for (int rg = 0; rg < 4; ++rg) v[rg] = (__bf16)(acc[i][j][rg] * scale);
        *(bf16x4*)(Cout + (((size_t)bb * 8 + hh) * 2048 + tok) * 64 + dd0) = v;
      } else {
        const int gm0 = m0 + wm + i * 16 + qd * 4;      // token (4 consecutive)
        const int gn = n0 + wn + j * 16 + ln;           // e
        const int bb = gm0 >> 11, tok0 = gm0 & 2047;
        const int hh = gn >> 6, dd = gn & 63;
        bf16x4 v;
#pragma unroll
        for (int rg = 0; rg < 4; ++rg) v[rg] = (__bf16)acc[i][j][rg];
        *(bf16x4*)(Cout + (((size_t)bb * 8 + hh) * 64 + dd) * 2048 + tok0) = v;
      }
    }
}

// Fused Q/K/V projections: grid (64, 12) = 768 blocks -> 3 blocks/CU.
__global__ __launch_bounds__(256, 3) void proj_qkv(
    const __bf16* __restrict__ xb, const __bf16* __restrict__ cb,
    const __bf16* __restrict__ Wq, const __bf16* __restrict__ Wk,
    const __bf16* __restrict__ Wv, __bf16* __restrict__ Qw,
    __bf16* __restrict__ Kw, __bf16* __restrict__ Vtw) {
  __shared__ __align__(16) __bf16 As[128][72];  // 18432B
  __shared__ __align__(16) __bf16 Bs[128][72];  // 18432B -> 36.9KB
  const int m0 = blockIdx.x * 128;
  const int job = blockIdx.y >> 2;  // 0=Q, 1=K, 2=V
  const int n0 = (blockIdx.y & 3) * 128;
  if (job == 0)
    gemm_body<0>(xb, Wq, Qw, 512, QSCALE, m0, n0, As, Bs);
  else if (job == 1)
    gemm_body<0>(cb, Wk, Kw, 768, 1.0f, m0, n0, As, Bs);
  else
    gemm_body<1>(cb, Wv, Vtw, 768, 1.0f, m0, n0, As, Bs);
}

// ---------------------------------------------------------------------------
// Final GEMM: out = ((O0+O1)/(l0+l1)) Wo^T + bo, fp32.  64x128 tile, BK=64,
// register-prefetch pipeline, grid (128,4)=512.  inv(l) hoisted.
// ---------------------------------------------------------------------------
__global__ __launch_bounds__(256) void gemm_out(
    const __bf16* __restrict__ O0, const __bf16* __restrict__ O1,
    const float* __restrict__ lbuf,  // [2][32][2048]
    const __bf16* __restrict__ B,    // Wo bf16 [512 x 512]
    float* __restrict__ C, const float* __restrict__ bias) {
  const int m0 = blockIdx.x * 64;
  const int n0 = blockIdx.y * 128;
  const int t = threadIdx.x;
  const int w = t >> 6;
  const int lane = t & 63;
  const int ln = lane & 15;
  const int qd = lane >> 4;
  const int wm = (w >> 1) * 32;
  const int wn = (w & 1) * 64;

  __shared__ __align__(16) __bf16 As[64][72];   //  9216B
  __shared__ __align__(16) __bf16 Bs[128][72];  // 18432B -> 27.6KB

  f32x4 zero4 = {0.f, 0.f, 0.f, 0.f};
  f32x4 acc[2][4];
#pragma unroll
  for (int i = 0; i < 2; ++i)
#pragma unroll
    for (int j = 0; j < 4; ++j) acc[i][j] = zero4;

  const int r0 = t >> 2;        // 0..63
  const int c0 = (t & 3) * 16;  // 0/16/32/48
  const int gm_s = m0 + r0;
  const int bidx = gm_s >> 11, tok_s = gm_s & 2047;
  const size_t aoff = (size_t)gm_s * 512 + c0;
  const __bf16* gB0 = B + (size_t)(n0 + r0) * 512 + c0;
  const __bf16* gB1 = B + (size_t)(n0 + r0 + 64) * 512 + c0;

  float inv[8];
#pragma unroll
  for (int hh = 0; hh < 8; ++hh) {
    const float l0 = lbuf[((size_t)bidx * 8 + hh) * 2048 + tok_s];
    const float l1 = lbuf[65536 + ((size_t)bidx * 8 + hh) * 2048 + tok_s];
    inv[hh] = 1.0f / (l0 + l1);
  }

  // prologue: load tile 0
  uint4 o00 = *(const uint4*)(O0 + aoff), o01 = *(const uint4*)(O0 + aoff + 8);
  uint4 o10 = *(const uint4*)(O1 + aoff), o11 = *(const uint4*)(O1 + aoff + 8);
  uint4 b00 = *(const uint4*)gB0, b01 = *(const uint4*)(gB0 + 8);
  uint4 b10 = *(const uint4*)gB1, b11 = *(const uint4*)(gB1 + 8);

  for (int kc = 0; kc < 512; kc += 64) {
    const float iv = inv[kc >> 6];
    union { bf16x8 v; uint4 u; } u0, u1, r0v, r1v;
    u0.u = o00; u1.u = o10;
#pragma unroll
    for (int e = 0; e < 8; ++e)
      r0v.v[e] = (__bf16)(((float)u0.v[e] + (float)u1.v[e]) * iv);
    u0.u = o01; u1.u = o11;
#pragma unroll
    for (int e = 0; e < 8; ++e)
      r1v.v[e] = (__bf16)(((float)u0.v[e] + (float)u1.v[e]) * iv);
    __syncthreads();
    *(uint4*)&As[r0][c0] = r0v.u;
    *(uint4*)&As[r0][c0 + 8] = r1v.u;
    *(uint4*)&Bs[r0][c0] = b00;       *(uint4*)&Bs[r0][c0 + 8] = b01;
    *(uint4*)&Bs[r0 + 64][c0] = b10;  *(uint4*)&Bs[r0 + 64][c0 + 8] = b11;
    __syncthreads();
    if (kc + 64 < 512) {
      o00 = *(const uint4*)(O0 + aoff + kc + 64);
      o01 = *(const uint4*)(O0 + aoff + kc + 72);
      o10 = *(const uint4*)(O1 + aoff + kc + 64);
      o11 = *(const uint4*)(O1 + aoff + kc + 72);
      b00 = *(const uint4*)(gB0 + kc + 64);
      b01 = *(const uint4*)(gB0 + kc + 72);
      b10 = *(const uint4*)(gB1 + kc + 64);
      b11 = *(const uint4*)(gB1 + kc + 72);
    }
#pragma unroll
    for (int kst = 0; kst < 2; ++kst) {
      bf16x8 af[2], bfr[4];
#pragma unroll
      for (int i = 0; i < 2; ++i)
        af[i] = *(const bf16x8*)&As[wm + i * 16 + ln][kst * 32 + qd * 8];
#pragma unroll
      for (int j = 0; j < 4; ++j)
        bfr[j] = *(const bf16x8*)&Bs[wn + j * 16 + ln][kst * 32 + qd * 8];
#pragma unroll
      for (int i = 0; i < 2; ++i)
#pragma unroll
        for (int j = 0; j < 4; ++j)
          acc[i][j] = mfma32(bfr[j], af[i], acc[i][j]);  // e->(qd,rg)
    }
  }

#pragma unroll
  for (int i = 0; i < 2; ++i)
#pragma unroll
    for (int j = 0; j < 4; ++j) {
      const int gm = m0 + wm + i * 16 + ln;
      const int gn0 = n0 + wn + j * 16 + qd * 4;
      f32x4 bi = *(const f32x4*)&bias[gn0];
      f32x4 v = acc[i][j] + bi;
      *(f32x4*)&C[(size_t)gm * 512 + gn0] = v;
    }
}

// ---------------------------------------------------------------------------
// Flash attention: S^T trick, raw-exp2 max-free softmax, Q in regs,
// sigma-permuted K rows -> x32 PV, ones-x32 l row-sum.
// R19 structure: 4 waves x 64 Q rows (256-thread blocks, BQ=256),
// KVBLK=128, split-K=2, ak/av frags amortized over 4 mt, dbuf
// single-barrier pipeline, reg prefetch 1 tile ahead, setprio.
// R28: 1-D grid (512) with T1 XCD swizzle — lin = (pair&7) + 8*qt +
// 64*(pair>>3), pair = bh*2+sp.  All 8 qt-blocks of a (bh,sp) pair share
// lin mod 8 -> same XCD -> K/V (256KB/pair, 2MB/XCD) stays L2-resident
// instead of being re-fetched by up to 8 XCDs (FETCH 71MB vs 25MB ideal).
// ---------------------------------------------------------------------------
__global__ __launch_bounds__(256, 2) void attn_kernel(
    const __bf16* __restrict__ Q,   // [BH][2048][64], pre-scaled by QSCALE
    const __bf16* __restrict__ K,   // [BH][2048][64]
    const __bf16* __restrict__ Vt,  // [BH][64][2048]
    __bf16* __restrict__ Oh,        // [2][B][2048][512] unnormalized
    float* __restrict__ lbuf) {     // [2][BH][2048]
  const int S = 2048;
  // T1 decode: lin = xslot + 8*qt + 64*phi; pair = xslot + 8*phi = bh*2+sp
  const int lin = blockIdx.x;
  const int xslot = lin & 7;
  const int qt = (lin >> 3) & 7;   // 8 Q tiles of 256 rows
  const int phi = lin >> 6;        // 0..7
  const int pair = xslot + 8 * phi;
  const int bh = pair >> 1;
  const int sp = pair & 1;
  const int b = bh >> 3, h = bh & 7;
  const int t = threadIdx.x;
  const int w = t >> 6;       // 0..3: wave owns Q rows qt*256 + w*64 ..
  const int lane = t & 63;
  const int ln = lane & 15;
  const int qd = lane >> 4;

  __shared__ __align__(16) __bf16 Ks[2][128][72];   // 36864B
  __shared__ __align__(16) __bf16 Vs[2][64][136];   // 34816B  total 71680B

  bf16x8 bq[4][2];  // [mt][kst] — 64 Q rows per wave
  {
    const __bf16* qb =
        Q + ((size_t)bh * S + qt * 256 + w * 64 + ln) * 64 + qd * 8;
#pragma unroll
    for (int mt = 0; mt < 4; ++mt)
#pragma unroll
      for (int kst = 0; kst < 2; ++kst)
        bq[mt][kst] = *(const bf16x8*)(qb + mt * 1024 + kst * 32);
  }

  f32x4 zero4 = {0.f, 0.f, 0.f, 0.f};
  f32x4 o[4][4];
  f32x4 o_l[4];
#pragma unroll
  for (int mt = 0; mt < 4; ++mt) {
#pragma unroll
    for (int i = 0; i < 4; ++i) o[mt][i] = zero4;
    o_l[mt] = zero4;
  }
  bf16x8 ones8;
  {
    union { unsigned short u[8]; bf16x8 v; } U;
#pragma unroll
    for (int e = 0; e < 8; ++e) U.u[e] = 0x3F80;  // bf16 1.0
    ones8 = U.v;
  }

  // K staging (256 threads): token row kr = t>>2 (0..63) and kr+64, 16 cols
  const int kr = t >> 2, kc0 = (t & 3) * 16;
  // sigma: token v -> row 16*((v>>2)&1) + 4*(v>>3) + (v&3) within 32-chunk
  const int krow =
      (kr & ~31) | ((kr & 4) << 2) | (((kr >> 3) & 3) << 2) | (kr & 3);
  // V staging: d-row vd = t>>3 (0..31) and vd+32, 16 tokens each
  const int vd = t >> 3, vtok0 = (t & 7) * 16;
  const int kt0 = sp * 8;

  // Hoisted global staging bases (advance by constants per tile).
  const __bf16* gK0 = K + ((size_t)bh * S + kt0 * 128 + kr) * 64 + kc0;
  const __bf16* gK1 = gK0 + 4096;   // row kr+64
  const __bf16* gV0 = Vt + ((size_t)bh * 64 + vd) * S + kt0 * 128 + vtok0;
  const __bf16* gV1 = gV0 + 65536;  // row vd+32

  // prologue: tile 0 -> LDS buf 0; prefetch tile 1 into regs; one barrier.
  {
    uint4 k00 = ((const uint4*)gK0)[0], k01 = ((const uint4*)gK0)[1];
    uint4 k10 = ((const uint4*)gK1)[0], k11 = ((const uint4*)gK1)[1];
    uint4 v00 = ((const uint4*)gV0)[0], v01 = ((const uint4*)gV0)[1];
    uint4 v10 = ((const uint4*)gV1)[0], v11 = ((const uint4*)gV1)[1];
    uint4* dK0 = (uint4*)&Ks[0][krow][kc0];      dK0[0] = k00; dK0[1] = k01;
    uint4* dK1 = (uint4*)&Ks[0][krow + 64][kc0]; dK1[0] = k10; dK1[1] = k11;
    uint4* dV0 = (uint4*)&Vs[0][vd][vtok0];      dV0[0] = v00; dV0[1] = v01;
    uint4* dV1 = (uint4*)&Vs[0][vd + 32][vtok0]; dV1[0] = v10; dV1[1] = v11;
  }
  uint4 pk00 = ((const uint4*)(gK0 + 8192))[0];
  uint4 pk01 = ((const uint4*)(gK0 + 8192))[1];
  uint4 pk10 = ((const uint4*)(gK1 + 8192))[0];
  uint4 pk11 = ((const uint4*)(gK1 + 8192))[1];
  uint4 pv00 = ((const uint4*)(gV0 + 128))[0];
  uint4 pv01 = ((const uint4*)(gV0 + 128))[1];
  uint4 pv10 = ((const uint4*)(gV1 + 128))[0];
  uint4 pv11 = ((const uint4*)(gV1 + 128))[1];
  __syncthreads();

  int p = 0;
  for (int it = 0; it < 8; ++it) {
    // stage tile it+1 into buf[p^1] (overlaps with compute on buf[p]);
    // issue global loads for tile it+2 (a full iteration of latency cover).
    if (it + 1 < 8) {
      uint4* dK0 = (uint4*)&Ks[p ^ 1][krow][kc0];
      dK0[0] = pk00; dK0[1] = pk01;
      uint4* dK1 = (uint4*)&Ks[p ^ 1][krow + 64][kc0];
      dK1[0] = pk10; dK1[1] = pk11;
      uint4* dV0 = (uint4*)&Vs[p ^ 1][vd][vtok0];
      dV0[0] = pv00; dV0[1] = pv01;
      uint4* dV1 = (uint4*)&Vs[p ^ 1][vd + 32][vtok0];
      dV1[0] = pv10; dV1[1] = pv11;
      if (it + 2 < 8) {
        const __bf16* nK0 = gK0 + (size_t)(it + 2) * 8192;
        const __bf16* nK1 = gK1 + (size_t)(it + 2) * 8192;
        const __bf16* nV0 = gV0 + (size_t)(it + 2) * 128;
        const __bf16* nV1 = gV1 + (size_t)(it + 2) * 128;
        pk00 = ((const uint4*)nK0)[0]; pk01 = ((const uint4*)nK0)[1];
        pk10 = ((const uint4*)nK1)[0]; pk11 = ((const uint4*)nK1)[1];
        pv00 = ((const uint4*)nV0)[0]; pv01 = ((const uint4*)nV0)[1];
        pv10 = ((const uint4*)nV1)[0]; pv11 = ((const uint4*)nV1)[1];
      }
    }

    const __bf16 (*Ksp)[72] = Ks[p];
    const __bf16 (*Vsp)[136] = Vs[p];

    // per 32-token chunk c: load ak/av frags ONCE, feed all 4 mt
#pragma unroll
    for (int c = 0; c < 4; ++c) {
      bf16x8 ak[2][2];  // [e][kst]
#pragma unroll
      for (int e = 0; e < 2; ++e)
#pragma unroll
        for (int kst = 0; kst < 2; ++kst)
          ak[e][kst] =
              *(const bf16x8*)&Ksp[(c * 2 + e) * 16 + ln][kst * 32 + qd * 8];
      bf16x8 av[4];
#pragma unroll
      for (int i = 0; i < 4; ++i)
        av[i] = *(const bf16x8*)&Vsp[i * 16 + ln][c * 32 + qd * 8];

#pragma unroll
      for (int mt = 0; mt < 4; ++mt) {
        f32x4 s0 = zero4, s1 = zero4;
        __builtin_amdgcn_s_setprio(1);
#pragma unroll
        for (int kst = 0; kst < 2; ++kst) {
          s0 = mfma32(ak[0][kst], bq[mt][kst], s0);
          s1 = mfma32(ak[1][kst], bq[mt][kst], s1);
        }
        __builtin_amdgcn_s_setprio(0);
#pragma unroll
        for (int rg = 0; rg < 4; ++rg) {
          s0[rg] = EXP2(s0[rg]);
          s1[rg] = EXP2(s1[rg]);
        }
        bf16x8 p2;  // P as x32 B-frag: lane holds tokens c*32 + qd*8 + j
#pragma unroll
        for (int rg = 0; rg < 4; ++rg) {
          p2[rg] = (__bf16)s0[rg];
          p2[rg + 4] = (__bf16)s1[rg];
        }
        __builtin_amdgcn_s_setprio(1);
        o_l[mt] = mfma32(ones8, p2, o_l[mt]);
#pragma unroll
        for (int i = 0; i < 4; ++i)
          o[mt][i] = mfma32(av[i], p2, o[mt][i]);
        __builtin_amdgcn_s_setprio(0);
      }
    }

    __syncthreads();  // buf[p^1] fully staged; buf[p] reads complete
    p ^= 1;
  }

  // ---- epilogue: write UNNORMALIZED O + l (combine happens in gemm_out)
  __bf16* Osp = Oh + (size_t)sp * 8192 * 512;
#pragma unroll
  for (int mt = 0; mt < 4; ++mt) {
    const int tok = qt * 256 + w * 64 + mt * 16 + ln;
    if (qd == 0) lbuf[((size_t)sp * 32 + bh) * 2048 + tok] = o_l[mt][0];
#pragma unroll
    for (int i = 0; i < 4; ++i) {
      bf16x4 v;
#pragma unroll
      for (int rg = 0; rg < 4; ++rg) v[rg] = (__bf16)o[mt][i][rg];
      const int col = h * 64 + i * 16 + qd * 4;
      *(bf16x4*)&Osp[((size_t)b * S + tok) * 512 + col] = v;
    }
  }
}

// ---------------------------------------------------------------------------
extern "C" void kernel_launch(void* const* d_in, const int* in_sizes, int n_in,
                              void* d_out, int out_size, void* d_ws,
                              size_t ws_size, hipStream_t stream) {
  const float* x = (const float*)d_in[0];
  const float* ctx = (const float*)d_in[1];
  const float* Wq = (const float*)d_in[2];
  const float* Wk = (const float*)d_in[3];
  const float* Wv = (const float*)d_in[4];
  const float* Wo = (const float*)d_in[5];
  const float* bo = (const float*)d_in[6];

  char* p = (char*)d_ws;
  __bf16* xb = (__bf16*)p;   p += (size_t)8192 * 512 * 2;
  __bf16* cb = (__bf16*)p;   p += (size_t)8192 * 768 * 2;
  __bf16* wqb = (__bf16*)p;  p += (size_t)512 * 512 * 2;
  __bf16* wkb = (__bf16*)p;  p += (size_t)512 * 768 * 2;
  __bf16* wvb = (__bf16*)p;  p += (size_t)512 * 768 * 2;
  __bf16* wob = (__bf16*)p;  p += (size_t)512 * 512 * 2;
  __bf16* Qw = (__bf16*)p;   p += (size_t)8192 * 512 * 2;
  __bf16* Kw = (__bf16*)p;   p += (size_t)8192 * 512 * 2;
  __bf16* Vtw = (__bf16*)p;  p += (size_t)8192 * 512 * 2;
  __bf16* Oh = (__bf16*)p;   p += (size_t)2 * 8192 * 512 * 2;
  float* lbuf = (float*)p;   p += (size_t)2 * 32 * 2048 * 4;

  cast_all<<<2880, 256, 0, stream>>>(x, ctx, Wq, Wk, Wv, Wo, xb, cb, wqb, wkb,
                                     wvb, wob);

  dim3 gp(64, 12);
  proj_qkv<<<gp, 256, 0, stream>>>(xb, cb, wqb, wkb, wvb, Qw, Kw, Vtw);

  attn_kernel<<<512, 256, 0, stream>>>(Qw, Kw, Vtw, Oh, lbuf);

  dim3 go(128, 4);
  gemm_out<<<go, 256, 0, stream>>>(Oh, Oh + (size_t)8192 * 512, lbuf, wob,
                                   (float*)d_out, bo);
}